// Round 4
// baseline (647.851 us; speedup 1.0000x reference)
//
#include <hip/hip_runtime.h>

// Problem constants
#define BB     2
#define CC     256
#define HH     48
#define WW     48
#define NTOK   2304          // H*W
#define NHEADS 8
#define HDIM   32
#define NBH    16            // BB*NHEADS
#define SCALE_QK 0.17677669529663687f  // 1/sqrt(32)
#define KSEL1  1152          // N1 // 2
#define KSEL2  768           // N1 // 3

typedef _Float16 f16x8 __attribute__((ext_vector_type(8)));
typedef float f32x4 __attribute__((ext_vector_type(4)));

__device__ __forceinline__ unsigned f2ord(float f) {
  unsigned u = __float_as_uint(f);
  return (u & 0x80000000u) ? ~u : (u | 0x80000000u);
}
__device__ __forceinline__ float ord2f(unsigned u) {
  unsigned b = (u & 0x80000000u) ? (u & 0x7fffffffu) : ~u;
  return __uint_as_float(b);
}

// ---------------------------------------------------------------------------
// Kernel A: multi-scale avg pool (3,5,7 box filters, count_include_pad) via
// per-plane integral image. One block per (b,c) plane.
__global__ __launch_bounds__(256) void pool_kernel(const float* __restrict__ y,
                                                   float* __restrict__ yp) {
  __shared__ float sp[HH * WW];
  __shared__ float I[49 * 49];
  const int bc = blockIdx.x;
  const float* src = y + (size_t)bc * (HH * WW);
  for (int i = threadIdx.x; i < HH * WW; i += 256) sp[i] = src[i];
  __syncthreads();
  if (threadIdx.x < 48) {            // row prefix sums
    int r = threadIdx.x;
    float acc = 0.f;
    I[(r + 1) * 49 + 0] = 0.f;
    for (int j = 0; j < 48; ++j) { acc += sp[r * 48 + j]; I[(r + 1) * 49 + j + 1] = acc; }
  } else if (threadIdx.x < 97) {     // zero top row
    int j = threadIdx.x - 48;
    I[j] = 0.f;
  }
  __syncthreads();
  if (threadIdx.x < 48) {            // column prefix sums
    int j = threadIdx.x + 1;
    float acc = 0.f;
    for (int i = 1; i <= 48; ++i) { acc += I[i * 49 + j]; I[i * 49 + j] = acc; }
  }
  __syncthreads();
  for (int n = threadIdx.x; n < HH * WW; n += 256) {
    int i = n / 48, j = n % 48;
    float r = 0.f;
#pragma unroll
    for (int kk = 0; kk < 3; ++kk) {
      int p = 1 + kk;                 // kernel 3,5,7 -> pad 1,2,3
      int i0 = i - p; if (i0 < 0) i0 = 0;
      int j0 = j - p; if (j0 < 0) j0 = 0;
      int i1 = i + p + 1; if (i1 > 48) i1 = 48;
      int j1 = j + p + 1; if (j1 > 48) j1 = 48;
      float s = I[i1 * 49 + j1] - I[i0 * 49 + j1] - I[i1 * 49 + j0] + I[i0 * 49 + j0];
      int k = 2 * p + 1;
      r += s / (float)(k * k);
    }
    yp[(size_t)bc * (HH * WW) + n] = r;
  }
}

// ---------------------------------------------------------------------------
// Kernel B: LayerNorm over C, transpose to [B, N, C]. One block per (b,n).
__global__ __launch_bounds__(256) void ln_kernel(const float* __restrict__ yp,
                                                 const float* __restrict__ gamma,
                                                 const float* __restrict__ beta,
                                                 float* __restrict__ yt) {
  const int bn = blockIdx.x;
  const int b = bn / NTOK, n = bn % NTOK;
  const int c = threadIdx.x;
  float v = yp[((size_t)(b * CC + c)) * NTOK + n];
  float s = v, s2 = v * v;
#pragma unroll
  for (int off = 32; off; off >>= 1) { s += __shfl_down(s, off); s2 += __shfl_down(s2, off); }
  __shared__ float ws[8];
  int wid = threadIdx.x >> 6, lane = threadIdx.x & 63;
  if (lane == 0) { ws[wid] = s; ws[4 + wid] = s2; }
  __syncthreads();
  s = ws[0] + ws[1] + ws[2] + ws[3];
  s2 = ws[4] + ws[5] + ws[6] + ws[7];
  float mean = s * (1.f / CC);
  float var = s2 * (1.f / CC) - mean * mean;
  float rstd = rsqrtf(var + 1e-5f);
  yt[(size_t)bn * CC + c] = (v - mean) * rstd * gamma[c] + beta[c];
}

// ---------------------------------------------------------------------------
// Generic 64x64-tile fp32 GEMM: C = A[M,K] @ B[K,Nc] (+bias).
// ATRANS=1: A is x in [B,C,N] layout, A[row,k] = x[b,k,n].
// trans_out=1: write Cm[b, col, n] (for the final projection into d_out).
template <int ATRANS>
__global__ __launch_bounds__(256) void gemm64_kernel(const float* __restrict__ A,
                                                     const float* __restrict__ Bm,
                                                     const float* __restrict__ bias,
                                                     float* __restrict__ Cm,
                                                     int K, int Nc, int trans_out) {
  __shared__ float smem[64 * 65];      // reused: As[16][68] + Bs[16][68], then Ts[64][65]
  float* As = smem;
  float* Bs = smem + 16 * 68;
  const int row0 = blockIdx.x * 64;
  const int col0 = blockIdx.y * 64;
  const int tid = threadIdx.x;
  const int ty = tid >> 4, tx = tid & 15;
  const int b = row0 / NTOK, n0 = row0 % NTOK;
  float acc[4][4] = {};
  for (int k0 = 0; k0 < K; k0 += 16) {
    if (ATRANS) {
#pragma unroll
      for (int it = 0; it < 4; ++it) {
        int idx = tid + it * 256;
        int kk = idx >> 6, r = idx & 63;
        As[kk * 68 + r] = A[((size_t)(b * CC + k0 + kk)) * NTOK + n0 + r];
      }
    } else {
#pragma unroll
      for (int it = 0; it < 4; ++it) {
        int idx = tid + it * 256;
        int kk = idx & 15, r = idx >> 4;
        As[kk * 68 + r] = A[(size_t)(row0 + r) * K + k0 + kk];
      }
    }
#pragma unroll
    for (int it = 0; it < 4; ++it) {
      int idx = tid + it * 256;
      int kk = idx >> 6, c = idx & 63;
      Bs[kk * 68 + c] = Bm[(size_t)(k0 + kk) * Nc + col0 + c];
    }
    __syncthreads();
#pragma unroll
    for (int kk = 0; kk < 16; ++kk) {
      float a0[4], b0[4];
#pragma unroll
      for (int i = 0; i < 4; ++i) a0[i] = As[kk * 68 + ty * 4 + i];
#pragma unroll
      for (int j = 0; j < 4; ++j) b0[j] = Bs[kk * 68 + tx * 4 + j];
#pragma unroll
      for (int i = 0; i < 4; ++i)
#pragma unroll
        for (int j = 0; j < 4; ++j) acc[i][j] += a0[i] * b0[j];
    }
    __syncthreads();
  }
  if (!trans_out) {
#pragma unroll
    for (int i = 0; i < 4; ++i)
#pragma unroll
      for (int j = 0; j < 4; ++j) {
        int row = row0 + ty * 4 + i, col = col0 + tx * 4 + j;
        float v = acc[i][j] + (bias ? bias[col] : 0.f);
        Cm[(size_t)row * Nc + col] = v;
      }
  } else {
    float* Ts = smem;
    __syncthreads();
#pragma unroll
    for (int i = 0; i < 4; ++i)
#pragma unroll
      for (int j = 0; j < 4; ++j) Ts[(ty * 4 + i) * 65 + tx * 4 + j] = acc[i][j];
    __syncthreads();
#pragma unroll
    for (int it = 0; it < 16; ++it) {
      int idx = tid + it * 256;
      int c = idx >> 6, r = idx & 63;
      float v = Ts[r * 65 + c] + (bias ? bias[col0 + c] : 0.f);
      Cm[((size_t)(b * Nc + col0 + c)) * NTOK + n0 + r] = v;
    }
  }
}

// ---------------------------------------------------------------------------
// Kernel D: scores = scale * q @ k^T, per (b,h) slice. Chunked over bh.
__global__ __launch_bounds__(256) void score_kernel(const float* __restrict__ qm,
                                                    const float* __restrict__ kvm,
                                                    float* __restrict__ sc, int bh0) {
  __shared__ float Qs[32 * 68];
  __shared__ float Ks[32 * 68];
  const int n0 = blockIdx.x * 64, m0 = blockIdx.y * 64;
  const int z = blockIdx.z;
  const int gbh = bh0 + z;
  const int b = gbh >> 3, h = gbh & 7;
  const int tid = threadIdx.x;
  {
    int kk = tid & 31, rb = tid >> 5;
#pragma unroll
    for (int i = 0; i < 8; ++i) {
      int r = rb * 8 + i;
      Qs[kk * 68 + r] = qm[((size_t)(b * NTOK + n0 + r)) * CC + h * HDIM + kk];
      Ks[kk * 68 + r] = kvm[((size_t)(b * NTOK + m0 + r)) * (2 * CC) + h * HDIM + kk];
    }
  }
  __syncthreads();
  const int ty = tid >> 4, tx = tid & 15;
  float acc[4][4] = {};
#pragma unroll
  for (int kk = 0; kk < 32; ++kk) {
    float a0[4], b0[4];
#pragma unroll
    for (int i = 0; i < 4; ++i) a0[i] = Qs[kk * 68 + ty * 4 + i];
#pragma unroll
    for (int j = 0; j < 4; ++j) b0[j] = Ks[kk * 68 + tx * 4 + j];
#pragma unroll
    for (int i = 0; i < 4; ++i)
#pragma unroll
      for (int j = 0; j < 4; ++j) acc[i][j] += a0[i] * b0[j];
  }
#pragma unroll
  for (int i = 0; i < 4; ++i) {
    size_t rowbase = ((size_t)z * NTOK + n0 + ty * 4 + i) * NTOK + m0;
#pragma unroll
    for (int j = 0; j < 4; ++j) sc[rowbase + tx * 4 + j] = acc[i][j] * SCALE_QK;
  }
}

// ---------------------------------------------------------------------------
// Suffix-scan bucket finder: one wave processes NB=NPL*64 bins from h,
// finds bucket where the running (descending) count crosses krem.
// Writes {bucket, new_krem} to sres2[0..1]. Exactly one lane-bin matches.
template <int NPL>
__device__ __forceinline__ void radix_find(const unsigned* __restrict__ h,
                                           unsigned krem, unsigned* sres2) {
  const int lane = threadIdx.x & 63;
  unsigned c[NPL];
#pragma unroll
  for (int i = 0; i < NPL; ++i) c[i] = h[lane * NPL + i];
  unsigned suf[NPL];
  unsigned run = 0;
#pragma unroll
  for (int i = NPL - 1; i >= 0; --i) { run += c[i]; suf[i] = run; }
  unsigned acc = run;
#pragma unroll
  for (int off = 1; off < 64; off <<= 1) {
    unsigned t = __shfl_down(acc, off);
    if (lane + off < 64) acc += t;
  }
  unsigned tail = __shfl_down(acc, 1);
  if (lane == 63) tail = 0;
#pragma unroll
  for (int i = 0; i < NPL; ++i) {
    unsigned s = tail + suf[i];
    unsigned nx = (i + 1 < NPL) ? (tail + suf[i + 1]) : tail;
    if (s >= krem && nx < krem) {
      sres2[0] = (unsigned)(lane * NPL + i);
      sres2[1] = krem - nx;
    }
  }
}

// ---------------------------------------------------------------------------
// Kernel E: per-row max, radix-select thresholds for k=1152 and k=768,
// partial exp-sums D1, D2. One block (256 threads) per score row.
// 3-level radix (10+11+11 bits): level-1 histogram is prefix-free and shared
// by both selections (fused into the load pass); levels 2/3 are ONE combined
// scan for both selections; suffix scans run on two waves in parallel.
// srow holds ordered uints so f2ord is computed exactly once per element.
__global__ __launch_bounds__(256) void select_kernel(const float* __restrict__ sc,
                                                     float* __restrict__ stats,
                                                     const float* __restrict__ w1p,
                                                     const float* __restrict__ w2p) {
  __shared__ unsigned srow[NTOK];
  __shared__ unsigned hists[2][2048];
  __shared__ unsigned umaxs[4];
  __shared__ float red[8];
  __shared__ unsigned sres[4];         // {bucket,krem} x 2 selections
  const int tid = threadIdx.x;
  const size_t base = (size_t)blockIdx.x * NTOK;

  for (int i = tid; i < 1024; i += 256) hists[0][i] = 0;
  __syncthreads();
  unsigned umax = 0;
  for (int j = tid; j < NTOK; j += 256) {
    float v = sc[base + j];
    unsigned u = f2ord(v);
    srow[j] = u;
    umax = max(umax, u);
    atomicAdd(&hists[0][u >> 22], 1u);
  }
#pragma unroll
  for (int off = 32; off; off >>= 1) umax = max(umax, __shfl_down(umax, off));
  if ((tid & 63) == 0) umaxs[tid >> 6] = umax;
  __syncthreads();
  const float mx = ord2f(max(max(umaxs[0], umaxs[1]), max(umaxs[2], umaxs[3])));

  // level 1 (bits 31..22): shared histogram, wave 0 finds both buckets
  if (tid < 64) {
    radix_find<16>(hists[0], KSEL1, &sres[0]);
    radix_find<16>(hists[0], KSEL2, &sres[2]);
  }
  __syncthreads();
  const unsigned p1 = sres[0];
  const unsigned p2 = sres[2];
  unsigned k1 = sres[1], k2 = sres[3];
  __syncthreads();
  for (int i = tid; i < 4096; i += 256) ((unsigned*)hists)[i] = 0;
  __syncthreads();

  // level 2 (bits 21..11): combined scan, both selections
  for (int j = tid; j < NTOK; j += 256) {
    unsigned u = srow[j];
    unsigned top = u >> 22;
    if (top == p1) atomicAdd(&hists[0][(u >> 11) & 2047u], 1u);
    if (top == p2) atomicAdd(&hists[1][(u >> 11) & 2047u], 1u);
  }
  __syncthreads();
  if (tid < 64)        radix_find<32>(hists[0], k1, &sres[0]);
  else if (tid < 128)  radix_find<32>(hists[1], k2, &sres[2]);
  __syncthreads();
  const unsigned q1 = (p1 << 11) | sres[0];
  const unsigned q2 = (p2 << 11) | sres[2];
  k1 = sres[1]; k2 = sres[3];
  __syncthreads();
  for (int i = tid; i < 4096; i += 256) ((unsigned*)hists)[i] = 0;
  __syncthreads();

  // level 3 (bits 10..0): combined scan
  for (int j = tid; j < NTOK; j += 256) {
    unsigned u = srow[j];
    unsigned top = u >> 11;
    if (top == q1) atomicAdd(&hists[0][u & 2047u], 1u);
    if (top == q2) atomicAdd(&hists[1][u & 2047u], 1u);
  }
  __syncthreads();
  if (tid < 64)        radix_find<32>(hists[0], k1, &sres[0]);
  else if (tid < 128)  radix_find<32>(hists[1], k2, &sres[2]);
  __syncthreads();
  const unsigned ut1 = (q1 << 11) | sres[0];
  const unsigned ut2 = (q2 << 11) | sres[2];

  // exp-sums (uint-domain threshold compares)
  float d1 = 0.f, d2 = 0.f;
  for (int j = tid; j < NTOK; j += 256) {
    unsigned u = srow[j];
    float e = __expf(ord2f(u) - mx);
    if (u >= ut1) d1 += e;
    if (u >= ut2) d2 += e;
  }
#pragma unroll
  for (int off = 32; off; off >>= 1) { d1 += __shfl_down(d1, off); d2 += __shfl_down(d2, off); }
  if ((tid & 63) == 0) { red[tid >> 6] = d1; red[4 + (tid >> 6)] = d2; }
  __syncthreads();
  if (tid == 0) {
    d1 = red[0] + red[1] + red[2] + red[3];
    d2 = red[4] + red[5] + red[6] + red[7];
    float* st = stats + (size_t)blockIdx.x * 8;
    st[0] = mx;
    st[1] = ord2f(ut1);
    st[2] = ord2f(ut2);
    st[3] = w1p[0] / d1;
    st[4] = w2p[0] / d2;
  }
}

// ---------------------------------------------------------------------------
// Kernel V: vtb[bh][d][m] = (f16) kv_v[b][m][h*32+d]  (transposed f16 V table)
__global__ __launch_bounds__(256) void vcast_kernel(const float* __restrict__ kvm,
                                                    _Float16* __restrict__ vtb) {
  int idx = blockIdx.x * 256 + threadIdx.x;   // over 16*32*2304
  int m = idx % NTOK;
  int t = idx / NTOK;          // bh*32 + d
  int d = t & 31;
  int bh = t >> 5;
  int b = bh >> 3, h = bh & 7;
  vtb[idx] = (_Float16)kvm[((size_t)(b * NTOK + m)) * (2 * CC) + CC + h * HDIM + d];
}

// ---------------------------------------------------------------------------
// Kernel F: PV via MFMA, zero LDS. Wave w of each block owns a 16(n) x 32(d)
// output tile. Per 32-m step: lane computes its 8 A-frag weights straight
// from the f32 score row (A layout: row=lane&15, k=(lane>>4)*8+i), converts
// to f16, MFMAs against the pre-transposed f16 V table. m-split over
// blockIdx.y, combined with atomicAdd into zeroed oat.
#define MSPLIT 4
__global__ __launch_bounds__(256) void pv_mfma_kernel(const float* __restrict__ sc,
                                                      const _Float16* __restrict__ vtb,
                                                      const float* __restrict__ stats,
                                                      float* __restrict__ oat, int bh0) {
  const int w = threadIdx.x >> 6;
  const int l = threadIdx.x & 63;
  const int z = blockIdx.z;
  const int gbh = bh0 + z;
  const int b = gbh >> 3, h = gbh & 7;
  const int n0 = blockIdx.x * 64 + w * 16;
  const int row = l & 15;            // A row / C col (d within half)
  const int kg = l >> 4;             // k-group
  const int n = n0 + row;
  const float* st = stats + ((size_t)z * NTOK + n) * 8;
  const float mx = st[0], t1 = st[1], t2 = st[2], w1d = st[3], w2d = st[4];
  const float* srow = sc + ((size_t)z * NTOK + n) * NTOK;
  const _Float16* v0 = vtb + ((size_t)gbh * HDIM + row) * NTOK;
  const _Float16* v1 = v0 + 16 * NTOK;
  f32x4 acc0 = {0.f, 0.f, 0.f, 0.f};
  f32x4 acc1 = {0.f, 0.f, 0.f, 0.f};
  const int msteps = (NTOK / 32) / MSPLIT;   // 18
  int m0 = blockIdx.y * msteps * 32 + kg * 8;
#pragma unroll 2
  for (int s = 0; s < msteps; ++s, m0 += 32) {
    f32x4 sa = *(const f32x4*)(srow + m0);
    f32x4 sb = *(const f32x4*)(srow + m0 + 4);
    f16x8 afr;
#pragma unroll
    for (int i = 0; i < 8; ++i) {
      float sv = (i < 4) ? sa[i] : sb[i - 4];
      float e = __expf(sv - mx);
      float wgt = (sv >= t1 ? w1d : 0.f) + (sv >= t2 ? w2d : 0.f);
      afr[i] = (_Float16)(e * wgt);
    }
    f16x8 bfr0 = *(const f16x8*)(v0 + m0);
    f16x8 bfr1 = *(const f16x8*)(v1 + m0);
    acc0 = __builtin_amdgcn_mfma_f32_16x16x32_f16(afr, bfr0, acc0, 0, 0, 0);
    acc1 = __builtin_amdgcn_mfma_f32_16x16x32_f16(afr, bfr1, acc1, 0, 0, 0);
  }
  // C/D layout: col = lane&15 (=row var), row = (lane>>4)*4 + reg
#pragma unroll
  for (int r = 0; r < 4; ++r) {
    int nn = n0 + kg * 4 + r;
    float* dst = &oat[((size_t)(b * NTOK + nn)) * CC + h * HDIM];
    atomicAdd(&dst[row], acc0[r]);
    atomicAdd(&dst[16 + row], acc1[r]);
  }
}

// ---------------------------------------------------------------------------
extern "C" void kernel_launch(void* const* d_in, const int* in_sizes, int n_in,
                              void* d_out, int out_size, void* d_ws, size_t ws_size,
                              hipStream_t stream) {
  const float* x     = (const float*)d_in[0];
  const float* y     = (const float*)d_in[1];
  const float* Wq    = (const float*)d_in[2];
  const float* Wkv   = (const float*)d_in[3];
  const float* Wproj = (const float*)d_in[4];
  const float* bproj = (const float*)d_in[5];
  const float* gamma = (const float*)d_in[6];
  const float* beta  = (const float*)d_in[7];
  const float* aw1   = (const float*)d_in[8];
  const float* aw2   = (const float*)d_in[9];

  float* ws = (float*)d_ws;
  const size_t SZ_PLANE = (size_t)BB * CC * NTOK;          // 1,179,648
  float* yp    = ws;                                       // [B,C,N]
  float* yt    = yp + SZ_PLANE;                            // [B,N,C]
  float* qb    = yt + SZ_PLANE;                            // [B,N,C]
  float* kvb   = qb + SZ_PLANE;                            // [B,N,2C]
  float* stats = kvb + 2 * SZ_PLANE;                       // [16*2304, 8]
  float* oat   = stats + (size_t)NBH * NTOK * 8;           // [B,N,C]
  _Float16* vtb = (_Float16*)(oat + SZ_PLANE);             // [16][32][2304] f16
  float* sc    = oat + SZ_PLANE + SZ_PLANE / 2;            // [CH, N, N]

  // choose bh-chunk size from available workspace; cap at 8 so the score
  // slice (170 MB) stays L3-resident (256 MB).
  const long long fixed_f = (long long)(sc - ws);
  const long long avail_f = (long long)(ws_size / 4) - fixed_f;
  int CH = 8;
  while (CH > 1 && (long long)CH * NTOK * NTOK > avail_f) CH >>= 1;

  pool_kernel<<<dim3(BB * CC), 256, 0, stream>>>(y, yp);
  ln_kernel<<<dim3(BB * NTOK), 256, 0, stream>>>(yp, gamma, beta, yt);
  gemm64_kernel<1><<<dim3(BB * NTOK / 64, CC / 64), 256, 0, stream>>>(
      x, Wq, nullptr, qb, CC, CC, 0);
  gemm64_kernel<0><<<dim3(BB * NTOK / 64, 2 * CC / 64), 256, 0, stream>>>(
      yt, Wkv, nullptr, kvb, CC, 2 * CC, 0);
  vcast_kernel<<<dim3((NBH * HDIM * NTOK) / 256), 256, 0, stream>>>(kvb, vtb);

  hipMemsetAsync(oat, 0, SZ_PLANE * sizeof(float), stream);

  const int nch = NBH / CH;
  for (int ch = 0; ch < nch; ++ch) {
    int bh0 = ch * CH;
    score_kernel<<<dim3(NTOK / 64, NTOK / 64, CH), 256, 0, stream>>>(qb, kvb, sc, bh0);
    select_kernel<<<dim3(CH * NTOK), 256, 0, stream>>>(sc, stats, aw1, aw2);
    pv_mfma_kernel<<<dim3(NTOK / 64, MSPLIT, CH), 256, 0, stream>>>(sc, vtb, stats, oat, bh0);
  }

  gemm64_kernel<0><<<dim3(BB * NTOK / 64, CC / 64), 256, 0, stream>>>(
      oat, Wproj, bproj, (float*)d_out, CC, CC, 1);
}

// Round 5
// 638.001 us; speedup vs baseline: 1.0154x; 1.0154x over previous
//
#include <hip/hip_runtime.h>

// Problem constants
#define BB     2
#define CC     256
#define HH     48
#define WW     48
#define NTOK   2304          // H*W
#define NHEADS 8
#define HDIM   32
#define NBH    16            // BB*NHEADS
#define SCALE_QK 0.17677669529663687f  // 1/sqrt(32)
#define KSEL1  1152          // N1 // 2
#define KSEL2  768           // N1 // 3
#define NBIN   512
#define GCAP   320

typedef _Float16 f16x8 __attribute__((ext_vector_type(8)));
typedef float f32x4 __attribute__((ext_vector_type(4)));

__device__ __forceinline__ unsigned f2ord(float f) {
  unsigned u = __float_as_uint(f);
  return (u & 0x80000000u) ? ~u : (u | 0x80000000u);
}
__device__ __forceinline__ float ord2f(unsigned u) {
  unsigned b = (u & 0x80000000u) ? (u & 0x7fffffffu) : ~u;
  return __uint_as_float(b);
}

// ---------------------------------------------------------------------------
// Kernel A: multi-scale avg pool (3,5,7 box filters, count_include_pad) via
// per-plane integral image. One block per (b,c) plane.
__global__ __launch_bounds__(256) void pool_kernel(const float* __restrict__ y,
                                                   float* __restrict__ yp) {
  __shared__ float sp[HH * WW];
  __shared__ float I[49 * 49];
  const int bc = blockIdx.x;
  const float* src = y + (size_t)bc * (HH * WW);
  for (int i = threadIdx.x; i < HH * WW; i += 256) sp[i] = src[i];
  __syncthreads();
  if (threadIdx.x < 48) {            // row prefix sums
    int r = threadIdx.x;
    float acc = 0.f;
    I[(r + 1) * 49 + 0] = 0.f;
    for (int j = 0; j < 48; ++j) { acc += sp[r * 48 + j]; I[(r + 1) * 49 + j + 1] = acc; }
  } else if (threadIdx.x < 97) {     // zero top row
    int j = threadIdx.x - 48;
    I[j] = 0.f;
  }
  __syncthreads();
  if (threadIdx.x < 48) {            // column prefix sums
    int j = threadIdx.x + 1;
    float acc = 0.f;
    for (int i = 1; i <= 48; ++i) { acc += I[i * 49 + j]; I[i * 49 + j] = acc; }
  }
  __syncthreads();
  for (int n = threadIdx.x; n < HH * WW; n += 256) {
    int i = n / 48, j = n % 48;
    float r = 0.f;
#pragma unroll
    for (int kk = 0; kk < 3; ++kk) {
      int p = 1 + kk;                 // kernel 3,5,7 -> pad 1,2,3
      int i0 = i - p; if (i0 < 0) i0 = 0;
      int j0 = j - p; if (j0 < 0) j0 = 0;
      int i1 = i + p + 1; if (i1 > 48) i1 = 48;
      int j1 = j + p + 1; if (j1 > 48) j1 = 48;
      float s = I[i1 * 49 + j1] - I[i0 * 49 + j1] - I[i1 * 49 + j0] + I[i0 * 49 + j0];
      int k = 2 * p + 1;
      r += s / (float)(k * k);
    }
    yp[(size_t)bc * (HH * WW) + n] = r;
  }
}

// ---------------------------------------------------------------------------
// Kernel B: LayerNorm over C, transpose to [B, N, C]. One block per (b,n).
__global__ __launch_bounds__(256) void ln_kernel(const float* __restrict__ yp,
                                                 const float* __restrict__ gamma,
                                                 const float* __restrict__ beta,
                                                 float* __restrict__ yt) {
  const int bn = blockIdx.x;
  const int b = bn / NTOK, n = bn % NTOK;
  const int c = threadIdx.x;
  float v = yp[((size_t)(b * CC + c)) * NTOK + n];
  float s = v, s2 = v * v;
#pragma unroll
  for (int off = 32; off; off >>= 1) { s += __shfl_down(s, off); s2 += __shfl_down(s2, off); }
  __shared__ float ws[8];
  int wid = threadIdx.x >> 6, lane = threadIdx.x & 63;
  if (lane == 0) { ws[wid] = s; ws[4 + wid] = s2; }
  __syncthreads();
  s = ws[0] + ws[1] + ws[2] + ws[3];
  s2 = ws[4] + ws[5] + ws[6] + ws[7];
  float mean = s * (1.f / CC);
  float var = s2 * (1.f / CC) - mean * mean;
  float rstd = rsqrtf(var + 1e-5f);
  yt[(size_t)bn * CC + c] = (v - mean) * rstd * gamma[c] + beta[c];
}

// ---------------------------------------------------------------------------
// Generic 64x64-tile fp32 GEMM: C = A[M,K] @ B[K,Nc] (+bias).
// ATRANS=1: A is x in [B,C,N] layout, A[row,k] = x[b,k,n].
// trans_out=1: write Cm[b, col, n] (for the final projection into d_out).
template <int ATRANS>
__global__ __launch_bounds__(256) void gemm64_kernel(const float* __restrict__ A,
                                                     const float* __restrict__ Bm,
                                                     const float* __restrict__ bias,
                                                     float* __restrict__ Cm,
                                                     int K, int Nc, int trans_out) {
  __shared__ float smem[64 * 65];      // reused: As[16][68] + Bs[16][68], then Ts[64][65]
  float* As = smem;
  float* Bs = smem + 16 * 68;
  const int row0 = blockIdx.x * 64;
  const int col0 = blockIdx.y * 64;
  const int tid = threadIdx.x;
  const int ty = tid >> 4, tx = tid & 15;
  const int b = row0 / NTOK, n0 = row0 % NTOK;
  float acc[4][4] = {};
  for (int k0 = 0; k0 < K; k0 += 16) {
    if (ATRANS) {
#pragma unroll
      for (int it = 0; it < 4; ++it) {
        int idx = tid + it * 256;
        int kk = idx >> 6, r = idx & 63;
        As[kk * 68 + r] = A[((size_t)(b * CC + k0 + kk)) * NTOK + n0 + r];
      }
    } else {
#pragma unroll
      for (int it = 0; it < 4; ++it) {
        int idx = tid + it * 256;
        int kk = idx & 15, r = idx >> 4;
        As[kk * 68 + r] = A[(size_t)(row0 + r) * K + k0 + kk];
      }
    }
#pragma unroll
    for (int it = 0; it < 4; ++it) {
      int idx = tid + it * 256;
      int kk = idx >> 6, c = idx & 63;
      Bs[kk * 68 + c] = Bm[(size_t)(k0 + kk) * Nc + col0 + c];
    }
    __syncthreads();
#pragma unroll
    for (int kk = 0; kk < 16; ++kk) {
      float a0[4], b0[4];
#pragma unroll
      for (int i = 0; i < 4; ++i) a0[i] = As[kk * 68 + ty * 4 + i];
#pragma unroll
      for (int j = 0; j < 4; ++j) b0[j] = Bs[kk * 68 + tx * 4 + j];
#pragma unroll
      for (int i = 0; i < 4; ++i)
#pragma unroll
        for (int j = 0; j < 4; ++j) acc[i][j] += a0[i] * b0[j];
    }
    __syncthreads();
  }
  if (!trans_out) {
#pragma unroll
    for (int i = 0; i < 4; ++i)
#pragma unroll
      for (int j = 0; j < 4; ++j) {
        int row = row0 + ty * 4 + i, col = col0 + tx * 4 + j;
        float v = acc[i][j] + (bias ? bias[col] : 0.f);
        Cm[(size_t)row * Nc + col] = v;
      }
  } else {
    float* Ts = smem;
    __syncthreads();
#pragma unroll
    for (int i = 0; i < 4; ++i)
#pragma unroll
      for (int j = 0; j < 4; ++j) Ts[(ty * 4 + i) * 65 + tx * 4 + j] = acc[i][j];
    __syncthreads();
#pragma unroll
    for (int it = 0; it < 16; ++it) {
      int idx = tid + it * 256;
      int c = idx >> 6, r = idx & 63;
      float v = Ts[r * 65 + c] + (bias ? bias[col0 + c] : 0.f);
      Cm[((size_t)(b * Nc + col0 + c)) * NTOK + n0 + r] = v;
    }
  }
}

// ---------------------------------------------------------------------------
// Kernel D: scores = scale * q @ k^T, per (b,h) slice. Chunked over bh.
// Also accumulates exact per-row min/max (f2ord domain) via global atomics,
// consumed by select_kernel for linear binning.
__global__ __launch_bounds__(256) void score_kernel(const float* __restrict__ qm,
                                                    const float* __restrict__ kvm,
                                                    float* __restrict__ sc,
                                                    unsigned* __restrict__ rminb,
                                                    unsigned* __restrict__ rmaxb,
                                                    int bh0) {
  __shared__ float Qs[32 * 68];
  __shared__ float Ks[32 * 68];
  const int n0 = blockIdx.x * 64, m0 = blockIdx.y * 64;
  const int z = blockIdx.z;
  const int gbh = bh0 + z;
  const int b = gbh >> 3, h = gbh & 7;
  const int tid = threadIdx.x;
  {
    int kk = tid & 31, rb = tid >> 5;
#pragma unroll
    for (int i = 0; i < 8; ++i) {
      int r = rb * 8 + i;
      Qs[kk * 68 + r] = qm[((size_t)(b * NTOK + n0 + r)) * CC + h * HDIM + kk];
      Ks[kk * 68 + r] = kvm[((size_t)(b * NTOK + m0 + r)) * (2 * CC) + h * HDIM + kk];
    }
  }
  __syncthreads();
  const int ty = tid >> 4, tx = tid & 15;
  float acc[4][4] = {};
#pragma unroll
  for (int kk = 0; kk < 32; ++kk) {
    float a0[4], b0[4];
#pragma unroll
    for (int i = 0; i < 4; ++i) a0[i] = Qs[kk * 68 + ty * 4 + i];
#pragma unroll
    for (int j = 0; j < 4; ++j) b0[j] = Ks[kk * 68 + tx * 4 + j];
#pragma unroll
    for (int i = 0; i < 4; ++i)
#pragma unroll
      for (int j = 0; j < 4; ++j) acc[i][j] += a0[i] * b0[j];
  }
#pragma unroll
  for (int i = 0; i < 4; ++i)
#pragma unroll
    for (int j = 0; j < 4; ++j) acc[i][j] *= SCALE_QK;
  // per-row min/max: reduce across the 16 tx-lanes (contiguous within wave)
#pragma unroll
  for (int i = 0; i < 4; ++i) {
    float vmax = fmaxf(fmaxf(acc[i][0], acc[i][1]), fmaxf(acc[i][2], acc[i][3]));
    float vmin = fminf(fminf(acc[i][0], acc[i][1]), fminf(acc[i][2], acc[i][3]));
#pragma unroll
    for (int off = 1; off < 16; off <<= 1) {
      vmax = fmaxf(vmax, __shfl_xor(vmax, off));
      vmin = fminf(vmin, __shfl_xor(vmin, off));
    }
    if (tx == 0) {
      int r = z * NTOK + n0 + ty * 4 + i;
      atomicMax(&rmaxb[r], f2ord(vmax));
      atomicMin(&rminb[r], f2ord(vmin));
    }
  }
#pragma unroll
  for (int i = 0; i < 4; ++i) {
    size_t rowbase = ((size_t)z * NTOK + n0 + ty * 4 + i) * NTOK + m0;
#pragma unroll
    for (int j = 0; j < 4; ++j) sc[rowbase + tx * 4 + j] = acc[i][j];
  }
}

// ---------------------------------------------------------------------------
// Suffix-scan bucket finder over NB=NPL*64 bins: finds bucket where the
// descending cumulative count crosses krem. Writes {bucket, new_krem}.
template <int NPL>
__device__ __forceinline__ void radix_find(const unsigned* __restrict__ h,
                                           unsigned krem, unsigned* sres2) {
  const int lane = threadIdx.x & 63;
  unsigned c[NPL];
#pragma unroll
  for (int i = 0; i < NPL; ++i) c[i] = h[lane * NPL + i];
  unsigned suf[NPL];
  unsigned run = 0;
#pragma unroll
  for (int i = NPL - 1; i >= 0; --i) { run += c[i]; suf[i] = run; }
  unsigned acc = run;
#pragma unroll
  for (int off = 1; off < 64; off <<= 1) {
    unsigned t = __shfl_down(acc, off);
    if (lane + off < 64) acc += t;
  }
  unsigned tail = __shfl_down(acc, 1);
  if (lane == 63) tail = 0;
#pragma unroll
  for (int i = 0; i < NPL; ++i) {
    unsigned s = tail + suf[i];
    unsigned nx = (i + 1 < NPL) ? (tail + suf[i + 1]) : tail;
    if (s >= krem && nx < krem) {
      sres2[0] = (unsigned)(lane * NPL + i);
      sres2[1] = krem - nx;
    }
  }
}

// ---------------------------------------------------------------------------
// Kernel E: thresholds for k=1152 / k=768 + exp-sums. One block per row.
// Value-domain linear histogram (512 bins over exact [min,max] from score
// kernel) -> near-zero atomic contention on Gaussian-ish data; boundary
// bucket (~14 elems) gathered and k-th found exactly by counting; final
// pass accumulates D1,D2 in registers (no atomics).
__global__ __launch_bounds__(256) void select_kernel(const float* __restrict__ sc,
                                                     const unsigned* __restrict__ rminb,
                                                     const unsigned* __restrict__ rmaxb,
                                                     float* __restrict__ stats,
                                                     const float* __restrict__ w1p,
                                                     const float* __restrict__ w2p) {
  __shared__ float srow[NTOK];
  __shared__ unsigned cnt[NBIN];
  __shared__ float buf[2][GCAP];
  __shared__ unsigned bcnt[2];
  __shared__ unsigned sres[4];
  __shared__ float tthr[2];
  __shared__ float red[8];
  const int tid = threadIdx.x;
  const int row = blockIdx.x;
  const size_t base = (size_t)row * NTOK;
  const float mx = ord2f(rmaxb[row]);
  const float lo = ord2f(rminb[row]);
  const float scale = (mx > lo) ? (float)NBIN / (mx - lo) : 0.f;
  for (int i = tid; i < NBIN; i += 256) cnt[i] = 0;
  if (tid < 2) bcnt[tid] = 0;
  __syncthreads();
  // fused load + linear histogram
  for (int j = tid; j < NTOK; j += 256) {
    float v = sc[base + j];
    srow[j] = v;
    int b = min((int)((v - lo) * scale), NBIN - 1);
    atomicAdd(&cnt[b], 1u);
  }
  __syncthreads();
  // find boundary buckets (two waves in parallel)
  if (tid < 64)        radix_find<NBIN / 64>(cnt, KSEL1, &sres[0]);
  else if (tid < 128)  radix_find<NBIN / 64>(cnt, KSEL2, &sres[2]);
  __syncthreads();
  const int b1 = (int)sres[0], b2 = (int)sres[2];
  const unsigned k1 = sres[1], k2 = sres[3];
  const unsigned c1 = cnt[b1], c2 = cnt[b2];
  const bool g1 = (c1 <= GCAP), g2 = (c2 <= GCAP);
  // gather boundary-bucket elements (both buckets in one pass)
  for (int j = tid; j < NTOK; j += 256) {
    float v = srow[j];
    int b = min((int)((v - lo) * scale), NBIN - 1);
    if (b == b1 && g1) buf[0][atomicAdd(&bcnt[0], 1u)] = v;
    if (b == b2 && g2) buf[1][atomicAdd(&bcnt[1], 1u)] = v;
  }
  __syncthreads();
  const int wv = tid >> 6, lane = tid & 63;
  if (wv < 2) {
    const int sel = wv;
    const unsigned kk = sel ? k2 : k1;
    const int bb = sel ? b2 : b1;
    const unsigned cc = sel ? c2 : c1;
    if (cc <= GCAP) {
      for (unsigned i = lane; i < cc; i += 64) {
        float x = buf[sel][i];
        unsigned g = 0, m = 0;
        for (unsigned j2 = 0; j2 < cc; ++j2) {
          float yv = buf[sel][j2];      // same-address broadcast, conflict-free
          g += (yv > x) ? 1u : 0u;
          m += (yv == x) ? 1u : 0u;
        }
        if (g < kk && kk <= g + m) tthr[sel] = x;
      }
    } else {
      // exact fallback (never triggered for non-degenerate data)
      for (int i = lane; i < NTOK; i += 64) {
        float x = srow[i];
        if (min((int)((x - lo) * scale), NBIN - 1) != bb) continue;
        unsigned g = 0, m = 0;
        for (int j2 = 0; j2 < NTOK; ++j2) {
          float yv = srow[j2];
          if (min((int)((yv - lo) * scale), NBIN - 1) != bb) continue;
          g += (yv > x) ? 1u : 0u;
          m += (yv == x) ? 1u : 0u;
        }
        if (g < kk && kk <= g + m) tthr[sel] = x;
      }
    }
  }
  __syncthreads();
  const float t1 = tthr[0], t2 = tthr[1];
  float d1 = 0.f, d2 = 0.f;
  for (int j = tid; j < NTOK; j += 256) {
    float v = srow[j];
    float e = __expf(v - mx);
    if (v >= t1) d1 += e;
    if (v >= t2) d2 += e;
  }
#pragma unroll
  for (int off = 32; off; off >>= 1) { d1 += __shfl_down(d1, off); d2 += __shfl_down(d2, off); }
  if (lane == 0) { red[wv] = d1; red[4 + wv] = d2; }
  __syncthreads();
  if (tid == 0) {
    d1 = red[0] + red[1] + red[2] + red[3];
    d2 = red[4] + red[5] + red[6] + red[7];
    float* st = stats + (size_t)row * 8;
    st[0] = mx;
    st[1] = t1;
    st[2] = t2;
    st[3] = w1p[0] / d1;
    st[4] = w2p[0] / d2;
  }
}

// ---------------------------------------------------------------------------
// Kernel V: vtb[bh][d][m] = (f16) kv_v[b][m][h*32+d]  (transposed f16 V table)
__global__ __launch_bounds__(256) void vcast_kernel(const float* __restrict__ kvm,
                                                    _Float16* __restrict__ vtb) {
  int idx = blockIdx.x * 256 + threadIdx.x;   // over 16*32*2304
  int m = idx % NTOK;
  int t = idx / NTOK;          // bh*32 + d
  int d = t & 31;
  int bh = t >> 5;
  int b = bh >> 3, h = bh & 7;
  vtb[idx] = (_Float16)kvm[((size_t)(b * NTOK + m)) * (2 * CC) + CC + h * HDIM + d];
}

// ---------------------------------------------------------------------------
// Kernel F: PV via MFMA, zero LDS. Wave w of each block owns a 16(n) x 32(d)
// output tile. Per 32-m step: lane computes its 8 A-frag weights straight
// from the f32 score row (A layout: row=lane&15, k=(lane>>4)*8+i), converts
// to f16, MFMAs against the pre-transposed f16 V table. m-split over
// blockIdx.y, combined with atomicAdd into zeroed oat.
#define MSPLIT 4
__global__ __launch_bounds__(256) void pv_mfma_kernel(const float* __restrict__ sc,
                                                      const _Float16* __restrict__ vtb,
                                                      const float* __restrict__ stats,
                                                      float* __restrict__ oat, int bh0) {
  const int w = threadIdx.x >> 6;
  const int l = threadIdx.x & 63;
  const int z = blockIdx.z;
  const int gbh = bh0 + z;
  const int b = gbh >> 3, h = gbh & 7;
  const int n0 = blockIdx.x * 64 + w * 16;
  const int row = l & 15;            // A row / C col (d within half)
  const int kg = l >> 4;             // k-group
  const int n = n0 + row;
  const float* st = stats + ((size_t)z * NTOK + n) * 8;
  const float mx = st[0], t1 = st[1], t2 = st[2], w1d = st[3], w2d = st[4];
  const float* srow = sc + ((size_t)z * NTOK + n) * NTOK;
  const _Float16* v0 = vtb + ((size_t)gbh * HDIM + row) * NTOK;
  const _Float16* v1 = v0 + 16 * NTOK;
  f32x4 acc0 = {0.f, 0.f, 0.f, 0.f};
  f32x4 acc1 = {0.f, 0.f, 0.f, 0.f};
  const int msteps = (NTOK / 32) / MSPLIT;   // 18
  int m0 = blockIdx.y * msteps * 32 + kg * 8;
#pragma unroll 2
  for (int s = 0; s < msteps; ++s, m0 += 32) {
    f32x4 sa = *(const f32x4*)(srow + m0);
    f32x4 sb = *(const f32x4*)(srow + m0 + 4);
    f16x8 afr;
#pragma unroll
    for (int i = 0; i < 8; ++i) {
      float sv = (i < 4) ? sa[i] : sb[i - 4];
      float e = __expf(sv - mx);
      float wgt = (sv >= t1 ? w1d : 0.f) + (sv >= t2 ? w2d : 0.f);
      afr[i] = (_Float16)(e * wgt);
    }
    f16x8 bfr0 = *(const f16x8*)(v0 + m0);
    f16x8 bfr1 = *(const f16x8*)(v1 + m0);
    acc0 = __builtin_amdgcn_mfma_f32_16x16x32_f16(afr, bfr0, acc0, 0, 0, 0);
    acc1 = __builtin_amdgcn_mfma_f32_16x16x32_f16(afr, bfr1, acc1, 0, 0, 0);
  }
  // C/D layout: col = lane&15 (=row var), row = (lane>>4)*4 + reg
#pragma unroll
  for (int r = 0; r < 4; ++r) {
    int nn = n0 + kg * 4 + r;
    float* dst = &oat[((size_t)(b * NTOK + nn)) * CC + h * HDIM];
    atomicAdd(&dst[row], acc0[r]);
    atomicAdd(&dst[16 + row], acc1[r]);
  }
}

// ---------------------------------------------------------------------------
extern "C" void kernel_launch(void* const* d_in, const int* in_sizes, int n_in,
                              void* d_out, int out_size, void* d_ws, size_t ws_size,
                              hipStream_t stream) {
  const float* x     = (const float*)d_in[0];
  const float* y     = (const float*)d_in[1];
  const float* Wq    = (const float*)d_in[2];
  const float* Wkv   = (const float*)d_in[3];
  const float* Wproj = (const float*)d_in[4];
  const float* bproj = (const float*)d_in[5];
  const float* gamma = (const float*)d_in[6];
  const float* beta  = (const float*)d_in[7];
  const float* aw1   = (const float*)d_in[8];
  const float* aw2   = (const float*)d_in[9];

  float* ws = (float*)d_ws;
  const size_t SZ_PLANE = (size_t)BB * CC * NTOK;          // 1,179,648
  float* yp    = ws;                                       // [B,C,N]
  float* yt    = yp + SZ_PLANE;                            // [B,N,C]
  float* qb    = yt + SZ_PLANE;                            // [B,N,C]
  float* kvb   = qb + SZ_PLANE;                            // [B,N,2C]
  float* stats = kvb + 2 * SZ_PLANE;                       // [16*2304, 8]
  float* oat   = stats + (size_t)NBH * NTOK * 8;           // [B,N,C]
  _Float16* vtb = (_Float16*)(oat + SZ_PLANE);             // [16][32][2304] f16
  unsigned* rmaxb = (unsigned*)(oat + SZ_PLANE + SZ_PLANE / 2);   // [8*NTOK]
  unsigned* rminb = rmaxb + 8 * NTOK;                      // [8*NTOK]
  float* sc    = (float*)(rminb + 8 * NTOK);               // [CH, N, N]

  // choose bh-chunk size from available workspace; cap at 8 so the score
  // slice (170 MB) stays L3-resident (256 MB).
  const long long fixed_f = (long long)(sc - ws);
  const long long avail_f = (long long)(ws_size / 4) - fixed_f;
  int CH = 8;
  while (CH > 1 && (long long)CH * NTOK * NTOK > avail_f) CH >>= 1;

  pool_kernel<<<dim3(BB * CC), 256, 0, stream>>>(y, yp);
  ln_kernel<<<dim3(BB * NTOK), 256, 0, stream>>>(yp, gamma, beta, yt);
  gemm64_kernel<1><<<dim3(BB * NTOK / 64, CC / 64), 256, 0, stream>>>(
      x, Wq, nullptr, qb, CC, CC, 0);
  gemm64_kernel<0><<<dim3(BB * NTOK / 64, 2 * CC / 64), 256, 0, stream>>>(
      yt, Wkv, nullptr, kvb, CC, 2 * CC, 0);
  vcast_kernel<<<dim3((NBH * HDIM * NTOK) / 256), 256, 0, stream>>>(kvb, vtb);

  hipMemsetAsync(oat, 0, SZ_PLANE * sizeof(float), stream);

  const int nch = NBH / CH;
  for (int ch = 0; ch < nch; ++ch) {
    int bh0 = ch * CH;
    hipMemsetAsync(rmaxb, 0x00, (size_t)CH * NTOK * 4, stream);
    hipMemsetAsync(rminb, 0xFF, (size_t)CH * NTOK * 4, stream);
    score_kernel<<<dim3(NTOK / 64, NTOK / 64, CH), 256, 0, stream>>>(
        qb, kvb, sc, rminb, rmaxb, bh0);
    select_kernel<<<dim3(CH * NTOK), 256, 0, stream>>>(sc, rminb, rmaxb, stats, aw1, aw2);
    pv_mfma_kernel<<<dim3(NTOK / 64, MSPLIT, CH), 256, 0, stream>>>(sc, vtb, stats, oat, bh0);
  }

  gemm64_kernel<0><<<dim3(BB * NTOK / 64, CC / 64), 256, 0, stream>>>(
      oat, Wproj, bproj, (float*)d_out, CC, CC, 1);
}

// Round 6
// 427.510 us; speedup vs baseline: 1.5154x; 1.4924x over previous
//
#include <hip/hip_runtime.h>

// Problem constants
#define BB     2
#define CC     256
#define HH     48
#define WW     48
#define NTOK   2304          // H*W
#define NHEADS 8
#define HDIM   32
#define NBH    16            // BB*NHEADS
#define SCALE_QK 0.17677669529663687f  // 1/sqrt(32)
#define KSEL1  1152          // N1 // 2
#define KSEL2  768           // N1 // 3
#define NBIN   512
#define GCAP   320
#define LOSCALE 2048.0f      // 2^11: keeps f16 lo-parts in normal range

typedef _Float16 f16x8 __attribute__((ext_vector_type(8)));
typedef float f32x4 __attribute__((ext_vector_type(4)));

// ---------------------------------------------------------------------------
// Kernel A: multi-scale avg pool (3,5,7 box filters, count_include_pad) via
// per-plane integral image. One block per (b,c) plane.
__global__ __launch_bounds__(256) void pool_kernel(const float* __restrict__ y,
                                                   float* __restrict__ yp) {
  __shared__ float sp[HH * WW];
  __shared__ float I[49 * 49];
  const int bc = blockIdx.x;
  const float* src = y + (size_t)bc * (HH * WW);
  for (int i = threadIdx.x; i < HH * WW; i += 256) sp[i] = src[i];
  __syncthreads();
  if (threadIdx.x < 48) {            // row prefix sums
    int r = threadIdx.x;
    float acc = 0.f;
    I[(r + 1) * 49 + 0] = 0.f;
    for (int j = 0; j < 48; ++j) { acc += sp[r * 48 + j]; I[(r + 1) * 49 + j + 1] = acc; }
  } else if (threadIdx.x < 97) {     // zero top row
    int j = threadIdx.x - 48;
    I[j] = 0.f;
  }
  __syncthreads();
  if (threadIdx.x < 48) {            // column prefix sums
    int j = threadIdx.x + 1;
    float acc = 0.f;
    for (int i = 1; i <= 48; ++i) { acc += I[i * 49 + j]; I[i * 49 + j] = acc; }
  }
  __syncthreads();
  for (int n = threadIdx.x; n < HH * WW; n += 256) {
    int i = n / 48, j = n % 48;
    float r = 0.f;
#pragma unroll
    for (int kk = 0; kk < 3; ++kk) {
      int p = 1 + kk;                 // kernel 3,5,7 -> pad 1,2,3
      int i0 = i - p; if (i0 < 0) i0 = 0;
      int j0 = j - p; if (j0 < 0) j0 = 0;
      int i1 = i + p + 1; if (i1 > 48) i1 = 48;
      int j1 = j + p + 1; if (j1 > 48) j1 = 48;
      float s = I[i1 * 49 + j1] - I[i0 * 49 + j1] - I[i1 * 49 + j0] + I[i0 * 49 + j0];
      int k = 2 * p + 1;
      r += s / (float)(k * k);
    }
    yp[(size_t)bc * (HH * WW) + n] = r;
  }
}

// ---------------------------------------------------------------------------
// Kernel B: LayerNorm over C, transpose to [B, N, C]. One block per (b,n).
__global__ __launch_bounds__(256) void ln_kernel(const float* __restrict__ yp,
                                                 const float* __restrict__ gamma,
                                                 const float* __restrict__ beta,
                                                 float* __restrict__ yt) {
  const int bn = blockIdx.x;
  const int b = bn / NTOK, n = bn % NTOK;
  const int c = threadIdx.x;
  float v = yp[((size_t)(b * CC + c)) * NTOK + n];
  float s = v, s2 = v * v;
#pragma unroll
  for (int off = 32; off; off >>= 1) { s += __shfl_down(s, off); s2 += __shfl_down(s2, off); }
  __shared__ float ws[8];
  int wid = threadIdx.x >> 6, lane = threadIdx.x & 63;
  if (lane == 0) { ws[wid] = s; ws[4 + wid] = s2; }
  __syncthreads();
  s = ws[0] + ws[1] + ws[2] + ws[3];
  s2 = ws[4] + ws[5] + ws[6] + ws[7];
  float mean = s * (1.f / CC);
  float var = s2 * (1.f / CC) - mean * mean;
  float rstd = rsqrtf(var + 1e-5f);
  yt[(size_t)bn * CC + c] = (v - mean) * rstd * gamma[c] + beta[c];
}

// ---------------------------------------------------------------------------
// Generic 64x64-tile fp32 GEMM: C = A[M,K] @ B[K,Nc] (+bias).
// ATRANS=1: A is x in [B,C,N] layout, A[row,k] = x[b,k,n].
// trans_out=1: write Cm[b, col, n] (for the final projection into d_out).
template <int ATRANS>
__global__ __launch_bounds__(256) void gemm64_kernel(const float* __restrict__ A,
                                                     const float* __restrict__ Bm,
                                                     const float* __restrict__ bias,
                                                     float* __restrict__ Cm,
                                                     int K, int Nc, int trans_out) {
  __shared__ float smem[64 * 65];      // reused: As[16][68] + Bs[16][68], then Ts[64][65]
  float* As = smem;
  float* Bs = smem + 16 * 68;
  const int row0 = blockIdx.x * 64;
  const int col0 = blockIdx.y * 64;
  const int tid = threadIdx.x;
  const int ty = tid >> 4, tx = tid & 15;
  const int b = row0 / NTOK, n0 = row0 % NTOK;
  float acc[4][4] = {};
  for (int k0 = 0; k0 < K; k0 += 16) {
    if (ATRANS) {
#pragma unroll
      for (int it = 0; it < 4; ++it) {
        int idx = tid + it * 256;
        int kk = idx >> 6, r = idx & 63;
        As[kk * 68 + r] = A[((size_t)(b * CC + k0 + kk)) * NTOK + n0 + r];
      }
    } else {
#pragma unroll
      for (int it = 0; it < 4; ++it) {
        int idx = tid + it * 256;
        int kk = idx & 15, r = idx >> 4;
        As[kk * 68 + r] = A[(size_t)(row0 + r) * K + k0 + kk];
      }
    }
#pragma unroll
    for (int it = 0; it < 4; ++it) {
      int idx = tid + it * 256;
      int kk = idx >> 6, c = idx & 63;
      Bs[kk * 68 + c] = Bm[(size_t)(k0 + kk) * Nc + col0 + c];
    }
    __syncthreads();
#pragma unroll
    for (int kk = 0; kk < 16; ++kk) {
      float a0[4], b0[4];
#pragma unroll
      for (int i = 0; i < 4; ++i) a0[i] = As[kk * 68 + ty * 4 + i];
#pragma unroll
      for (int j = 0; j < 4; ++j) b0[j] = Bs[kk * 68 + tx * 4 + j];
#pragma unroll
      for (int i = 0; i < 4; ++i)
#pragma unroll
        for (int j = 0; j < 4; ++j) acc[i][j] += a0[i] * b0[j];
    }
    __syncthreads();
  }
  if (!trans_out) {
#pragma unroll
    for (int i = 0; i < 4; ++i)
#pragma unroll
      for (int j = 0; j < 4; ++j) {
        int row = row0 + ty * 4 + i, col = col0 + tx * 4 + j;
        float v = acc[i][j] + (bias ? bias[col] : 0.f);
        Cm[(size_t)row * Nc + col] = v;
      }
  } else {
    float* Ts = smem;
    __syncthreads();
#pragma unroll
    for (int i = 0; i < 4; ++i)
#pragma unroll
      for (int j = 0; j < 4; ++j) Ts[(ty * 4 + i) * 65 + tx * 4 + j] = acc[i][j];
    __syncthreads();
#pragma unroll
    for (int it = 0; it < 16; ++it) {
      int idx = tid + it * 256;
      int c = idx >> 6, r = idx & 63;
      float v = Ts[r * 65 + c] + (bias ? bias[col0 + c] : 0.f);
      Cm[((size_t)(b * Nc + col0 + c)) * NTOK + n0 + r] = v;
    }
  }
}

// ---------------------------------------------------------------------------
// Kernel Q: build f16 hi/lo MFMA operand tables.
// qh/ql: (q * SCALE) split; kh/kl: k split; lo parts scaled by 2^11 so they
// stay in f16 normal range. Layout [gbh][n][32] -> one 16B load per fragment.
__global__ __launch_bounds__(256) void qkcast_kernel(const float* __restrict__ qm,
                                                     const float* __restrict__ kvm,
                                                     _Float16* __restrict__ qh,
                                                     _Float16* __restrict__ ql,
                                                     _Float16* __restrict__ kh,
                                                     _Float16* __restrict__ kl) {
  int idx = blockIdx.x * 256 + threadIdx.x;   // over NBH*NTOK*HDIM
  int d = idx & 31;
  int n = (idx >> 5) % NTOK;
  int gbh = idx / (NTOK * HDIM);
  int b = gbh >> 3, h = gbh & 7;
  float qs = qm[((size_t)(b * NTOK + n)) * CC + h * HDIM + d] * SCALE_QK;
  _Float16 hi = (_Float16)qs;
  qh[idx] = hi;
  ql[idx] = (_Float16)((qs - (float)hi) * LOSCALE);
  float ks = kvm[((size_t)(b * NTOK + n)) * (2 * CC) + h * HDIM + d];
  hi = (_Float16)ks;
  kh[idx] = hi;
  kl[idx] = (_Float16)((ks - (float)hi) * LOSCALE);
}

// ---------------------------------------------------------------------------
// Kernel D: scores via MFMA with f16 hi/lo split precision (error ~2e-7,
// preserves the reference top-k set). Zero LDS. Wave = 32n x 32m (2x2 tiles
// of 16x16x32); block = 4 waves = 64n x 64m, m-loop x4 -> 64n x 256m.
// score = hi*hi + (hi*lo' + lo'*hi)/2048, accumulated in two f32 MFMA accs.
#define SMSTEP 4
__global__ __launch_bounds__(256) void score_mfma_kernel(const _Float16* __restrict__ qh,
                                                         const _Float16* __restrict__ ql,
                                                         const _Float16* __restrict__ kh,
                                                         const _Float16* __restrict__ kl,
                                                         float* __restrict__ sc, int bh0) {
  const int w = threadIdx.x >> 6;
  const int lane = threadIdx.x & 63;
  const int wn = w >> 1, wm = w & 1;
  const int r16 = lane & 15, kg = lane >> 4;
  const int z = blockIdx.z;
  const int gbh = bh0 + z;
  const size_t tb = (size_t)gbh * NTOK * HDIM;
  const int n0 = blockIdx.x * 64 + wn * 32;
  const f32x4 fz = {0.f, 0.f, 0.f, 0.f};
  f16x8 ah[2], al[2];
#pragma unroll
  for (int i = 0; i < 2; ++i) {
    size_t off = tb + (size_t)(n0 + i * 16 + r16) * HDIM + kg * 8;
    ah[i] = *(const f16x8*)(qh + off);
    al[i] = *(const f16x8*)(ql + off);
  }
  for (int s = 0; s < SMSTEP; ++s) {
    const int ms = blockIdx.y * (SMSTEP * 64) + s * 64 + wm * 32;
    f16x8 bhf[2], blf[2];
#pragma unroll
    for (int j = 0; j < 2; ++j) {
      size_t off = tb + (size_t)(ms + j * 16 + r16) * HDIM + kg * 8;
      bhf[j] = *(const f16x8*)(kh + off);
      blf[j] = *(const f16x8*)(kl + off);
    }
#pragma unroll
    for (int i = 0; i < 2; ++i)
#pragma unroll
      for (int j = 0; j < 2; ++j) {
        f32x4 acc = __builtin_amdgcn_mfma_f32_16x16x32_f16(ah[i], bhf[j], fz, 0, 0, 0);
        f32x4 ac2 = __builtin_amdgcn_mfma_f32_16x16x32_f16(ah[i], blf[j], fz, 0, 0, 0);
        ac2 = __builtin_amdgcn_mfma_f32_16x16x32_f16(al[i], bhf[j], ac2, 0, 0, 0);
        // C layout: row=(lane>>4)*4+r (q row), col=lane&15 (m col)
        size_t rowbase = ((size_t)z * NTOK + n0 + i * 16 + kg * 4) * NTOK + ms + j * 16 + r16;
#pragma unroll
        for (int r = 0; r < 4; ++r)
          sc[rowbase + (size_t)r * NTOK] = acc[r] + ac2[r] * (1.0f / LOSCALE);
      }
  }
}

// ---------------------------------------------------------------------------
// Suffix-scan bucket finder over NB=NPL*64 bins: finds bucket where the
// descending cumulative count crosses krem. Writes {bucket, new_krem}.
template <int NPL>
__device__ __forceinline__ void radix_find(const unsigned* __restrict__ h,
                                           unsigned krem, unsigned* sres2) {
  const int lane = threadIdx.x & 63;
  unsigned c[NPL];
#pragma unroll
  for (int i = 0; i < NPL; ++i) c[i] = h[lane * NPL + i];
  unsigned suf[NPL];
  unsigned run = 0;
#pragma unroll
  for (int i = NPL - 1; i >= 0; --i) { run += c[i]; suf[i] = run; }
  unsigned acc = run;
#pragma unroll
  for (int off = 1; off < 64; off <<= 1) {
    unsigned t = __shfl_down(acc, off);
    if (lane + off < 64) acc += t;
  }
  unsigned tail = __shfl_down(acc, 1);
  if (lane == 63) tail = 0;
#pragma unroll
  for (int i = 0; i < NPL; ++i) {
    unsigned s = tail + suf[i];
    unsigned nx = (i + 1 < NPL) ? (tail + suf[i + 1]) : tail;
    if (s >= krem && nx < krem) {
      sres2[0] = (unsigned)(lane * NPL + i);
      sres2[1] = krem - nx;
    }
  }
}

// ---------------------------------------------------------------------------
// Kernel E: thresholds for k=1152 / k=768 + exp-sums. One block per row.
// Pass 1: load row to LDS + exact min/max block-reduce. Pass 2: value-domain
// linear histogram (512 bins, near-zero atomic contention). Boundary bucket
// gathered, k-th found exactly by counting. Final pass: D1,D2 in registers.
__global__ __launch_bounds__(256) void select_kernel(const float* __restrict__ sc,
                                                     float* __restrict__ stats,
                                                     const float* __restrict__ w1p,
                                                     const float* __restrict__ w2p) {
  __shared__ float srow[NTOK];
  __shared__ unsigned cnt[NBIN];
  __shared__ float buf[2][GCAP];
  __shared__ unsigned bcnt[2];
  __shared__ unsigned sres[4];
  __shared__ float tthr[2];
  __shared__ float red[8];
  const int tid = threadIdx.x;
  const int row = blockIdx.x;
  const size_t base = (size_t)row * NTOK;
  const int wv = tid >> 6, lane = tid & 63;
  for (int i = tid; i < NBIN; i += 256) cnt[i] = 0;
  if (tid < 2) bcnt[tid] = 0;
  // pass 1: load + min/max
  float tmax = -3.4e38f, tmin = 3.4e38f;
  for (int j = tid; j < NTOK; j += 256) {
    float v = sc[base + j];
    srow[j] = v;
    tmax = fmaxf(tmax, v);
    tmin = fminf(tmin, v);
  }
#pragma unroll
  for (int off = 32; off; off >>= 1) {
    tmax = fmaxf(tmax, __shfl_down(tmax, off));
    tmin = fminf(tmin, __shfl_down(tmin, off));
  }
  if (lane == 0) { red[wv] = tmax; red[4 + wv] = tmin; }
  __syncthreads();
  const float mx = fmaxf(fmaxf(red[0], red[1]), fmaxf(red[2], red[3]));
  const float lo = fminf(fminf(red[4], red[5]), fminf(red[6], red[7]));
  const float scale = (mx > lo) ? (float)NBIN / (mx - lo) : 0.f;
  // pass 2: histogram from LDS
  for (int j = tid; j < NTOK; j += 256) {
    int b = min((int)((srow[j] - lo) * scale), NBIN - 1);
    atomicAdd(&cnt[b], 1u);
  }
  __syncthreads();
  // find boundary buckets (two waves in parallel)
  if (tid < 64)        radix_find<NBIN / 64>(cnt, KSEL1, &sres[0]);
  else if (tid < 128)  radix_find<NBIN / 64>(cnt, KSEL2, &sres[2]);
  __syncthreads();
  const int b1 = (int)sres[0], b2 = (int)sres[2];
  const unsigned k1 = sres[1], k2 = sres[3];
  const unsigned c1 = cnt[b1], c2 = cnt[b2];
  const bool g1 = (c1 <= GCAP), g2 = (c2 <= GCAP);
  // gather boundary-bucket elements (both buckets in one pass)
  for (int j = tid; j < NTOK; j += 256) {
    float v = srow[j];
    int b = min((int)((v - lo) * scale), NBIN - 1);
    if (b == b1 && g1) buf[0][atomicAdd(&bcnt[0], 1u)] = v;
    if (b == b2 && g2) buf[1][atomicAdd(&bcnt[1], 1u)] = v;
  }
  __syncthreads();
  if (wv < 2) {
    const int sel = wv;
    const unsigned kk = sel ? k2 : k1;
    const int bb = sel ? b2 : b1;
    const unsigned cc = sel ? c2 : c1;
    if (cc <= GCAP) {
      for (unsigned i = lane; i < cc; i += 64) {
        float x = buf[sel][i];
        unsigned g = 0, m = 0;
        for (unsigned j2 = 0; j2 < cc; ++j2) {
          float yv = buf[sel][j2];      // same-address broadcast, conflict-free
          g += (yv > x) ? 1u : 0u;
          m += (yv == x) ? 1u : 0u;
        }
        if (g < kk && kk <= g + m) tthr[sel] = x;
      }
    } else {
      // exact fallback (never triggered for non-degenerate data)
      for (int i = lane; i < NTOK; i += 64) {
        float x = srow[i];
        if (min((int)((x - lo) * scale), NBIN - 1) != bb) continue;
        unsigned g = 0, m = 0;
        for (int j2 = 0; j2 < NTOK; ++j2) {
          float yv = srow[j2];
          if (min((int)((yv - lo) * scale), NBIN - 1) != bb) continue;
          g += (yv > x) ? 1u : 0u;
          m += (yv == x) ? 1u : 0u;
        }
        if (g < kk && kk <= g + m) tthr[sel] = x;
      }
    }
  }
  __syncthreads();
  const float t1 = tthr[0], t2 = tthr[1];
  float d1 = 0.f, d2 = 0.f;
  for (int j = tid; j < NTOK; j += 256) {
    float v = srow[j];
    float e = __expf(v - mx);
    if (v >= t1) d1 += e;
    if (v >= t2) d2 += e;
  }
#pragma unroll
  for (int off = 32; off; off >>= 1) { d1 += __shfl_down(d1, off); d2 += __shfl_down(d2, off); }
  if (lane == 0) { red[wv] = d1; red[4 + wv] = d2; }
  __syncthreads();
  if (tid == 0) {
    d1 = red[0] + red[1] + red[2] + red[3];
    d2 = red[4] + red[5] + red[6] + red[7];
    float* st = stats + (size_t)row * 8;
    st[0] = mx;
    st[1] = t1;
    st[2] = t2;
    st[3] = w1p[0] / d1;
    st[4] = w2p[0] / d2;
  }
}

// ---------------------------------------------------------------------------
// Kernel V: vtb[bh][d][m] = (f16) kv_v[b][m][h*32+d]  (transposed f16 V table)
__global__ __launch_bounds__(256) void vcast_kernel(const float* __restrict__ kvm,
                                                    _Float16* __restrict__ vtb) {
  int idx = blockIdx.x * 256 + threadIdx.x;   // over 16*32*2304
  int m = idx % NTOK;
  int t = idx / NTOK;          // bh*32 + d
  int d = t & 31;
  int bh = t >> 5;
  int b = bh >> 3, h = bh & 7;
  vtb[idx] = (_Float16)kvm[((size_t)(b * NTOK + m)) * (2 * CC) + CC + h * HDIM + d];
}

// ---------------------------------------------------------------------------
// Kernel F: PV via MFMA, zero LDS. Wave w of each block owns a 16(n) x 32(d)
// output tile. Per 32-m step: lane computes its 8 A-frag weights straight
// from the f32 score row (A layout: row=lane&15, k=(lane>>4)*8+i), converts
// to f16, MFMAs against the pre-transposed f16 V table. m-split over
// blockIdx.y, combined with atomicAdd into zeroed oat.
#define MSPLIT 4
__global__ __launch_bounds__(256) void pv_mfma_kernel(const float* __restrict__ sc,
                                                      const _Float16* __restrict__ vtb,
                                                      const float* __restrict__ stats,
                                                      float* __restrict__ oat, int bh0) {
  const int w = threadIdx.x >> 6;
  const int l = threadIdx.x & 63;
  const int z = blockIdx.z;
  const int gbh = bh0 + z;
  const int b = gbh >> 3, h = gbh & 7;
  const int n0 = blockIdx.x * 64 + w * 16;
  const int row = l & 15;            // A row / C col (d within half)
  const int kg = l >> 4;             // k-group
  const int n = n0 + row;
  const float* st = stats + ((size_t)z * NTOK + n) * 8;
  const float mx = st[0], t1 = st[1], t2 = st[2], w1d = st[3], w2d = st[4];
  const float* srow = sc + ((size_t)z * NTOK + n) * NTOK;
  const _Float16* v0 = vtb + ((size_t)gbh * HDIM + row) * NTOK;
  const _Float16* v1 = v0 + 16 * NTOK;
  f32x4 acc0 = {0.f, 0.f, 0.f, 0.f};
  f32x4 acc1 = {0.f, 0.f, 0.f, 0.f};
  const int msteps = (NTOK / 32) / MSPLIT;   // 18
  int m0 = blockIdx.y * msteps * 32 + kg * 8;
#pragma unroll 2
  for (int s = 0; s < msteps; ++s, m0 += 32) {
    f32x4 sa = *(const f32x4*)(srow + m0);
    f32x4 sb = *(const f32x4*)(srow + m0 + 4);
    f16x8 afr;
#pragma unroll
    for (int i = 0; i < 8; ++i) {
      float sv = (i < 4) ? sa[i] : sb[i - 4];
      float e = __expf(sv - mx);
      float wgt = (sv >= t1 ? w1d : 0.f) + (sv >= t2 ? w2d : 0.f);
      afr[i] = (_Float16)(e * wgt);
    }
    f16x8 bfr0 = *(const f16x8*)(v0 + m0);
    f16x8 bfr1 = *(const f16x8*)(v1 + m0);
    acc0 = __builtin_amdgcn_mfma_f32_16x16x32_f16(afr, bfr0, acc0, 0, 0, 0);
    acc1 = __builtin_amdgcn_mfma_f32_16x16x32_f16(afr, bfr1, acc1, 0, 0, 0);
  }
  // C/D layout: col = lane&15 (=row var), row = (lane>>4)*4 + reg
#pragma unroll
  for (int r = 0; r < 4; ++r) {
    int nn = n0 + kg * 4 + r;
    float* dst = &oat[((size_t)(b * NTOK + nn)) * CC + h * HDIM];
    atomicAdd(&dst[row], acc0[r]);
    atomicAdd(&dst[16 + row], acc1[r]);
  }
}

// ---------------------------------------------------------------------------
extern "C" void kernel_launch(void* const* d_in, const int* in_sizes, int n_in,
                              void* d_out, int out_size, void* d_ws, size_t ws_size,
                              hipStream_t stream) {
  const float* x     = (const float*)d_in[0];
  const float* y     = (const float*)d_in[1];
  const float* Wq    = (const float*)d_in[2];
  const float* Wkv   = (const float*)d_in[3];
  const float* Wproj = (const float*)d_in[4];
  const float* bproj = (const float*)d_in[5];
  const float* gamma = (const float*)d_in[6];
  const float* beta  = (const float*)d_in[7];
  const float* aw1   = (const float*)d_in[8];
  const float* aw2   = (const float*)d_in[9];

  float* ws = (float*)d_ws;
  const size_t SZ_PLANE = (size_t)BB * CC * NTOK;          // 1,179,648
  const size_t SZ_TBL = (size_t)NBH * NTOK * HDIM;         // 1,179,648 (f16 elems)
  float* yp    = ws;                                       // [B,C,N]
  float* yt    = yp + SZ_PLANE;                            // [B,N,C]
  float* qb    = yt + SZ_PLANE;                            // [B,N,C]
  float* kvb   = qb + SZ_PLANE;                            // [B,N,2C]
  float* stats = kvb + 2 * SZ_PLANE;                       // [16*2304, 8]
  float* oat   = stats + (size_t)NBH * NTOK * 8;           // [B,N,C]
  _Float16* vtb = (_Float16*)(oat + SZ_PLANE);             // [16][32][2304] f16
  _Float16* qh = vtb + SZ_TBL;                             // [16][2304][32] f16
  _Float16* ql = qh + SZ_TBL;
  _Float16* kh = ql + SZ_TBL;
  _Float16* kl = kh + SZ_TBL;
  float* sc    = (float*)(kl + SZ_TBL);                    // [CH, N, N]

  // choose bh-chunk size from available workspace; cap at 8 so the score
  // slice (170 MB) stays L3-resident (256 MB).
  const long long fixed_f = (long long)(sc - ws);
  const long long avail_f = (long long)(ws_size / 4) - fixed_f;
  int CH = 8;
  while (CH > 1 && (long long)CH * NTOK * NTOK > avail_f) CH >>= 1;

  pool_kernel<<<dim3(BB * CC), 256, 0, stream>>>(y, yp);
  ln_kernel<<<dim3(BB * NTOK), 256, 0, stream>>>(yp, gamma, beta, yt);
  gemm64_kernel<1><<<dim3(BB * NTOK / 64, CC / 64), 256, 0, stream>>>(
      x, Wq, nullptr, qb, CC, CC, 0);
  gemm64_kernel<0><<<dim3(BB * NTOK / 64, 2 * CC / 64), 256, 0, stream>>>(
      yt, Wkv, nullptr, kvb, CC, 2 * CC, 0);
  vcast_kernel<<<dim3((NBH * HDIM * NTOK) / 256), 256, 0, stream>>>(kvb, vtb);
  qkcast_kernel<<<dim3((NBH * NTOK * HDIM) / 256), 256, 0, stream>>>(
      qb, kvb, qh, ql, kh, kl);

  hipMemsetAsync(oat, 0, SZ_PLANE * sizeof(float), stream);

  const int nch = NBH / CH;
  for (int ch = 0; ch < nch; ++ch) {
    int bh0 = ch * CH;
    score_mfma_kernel<<<dim3(NTOK / 64, NTOK / (SMSTEP * 64), CH), 256, 0, stream>>>(
        qh, ql, kh, kl, sc, bh0);
    select_kernel<<<dim3(CH * NTOK), 256, 0, stream>>>(sc, stats, aw1, aw2);
    pv_mfma_kernel<<<dim3(NTOK / 64, MSPLIT, CH), 256, 0, stream>>>(sc, vtb, stats, oat, bh0);
  }

  gemm64_kernel<0><<<dim3(BB * NTOK / 64, CC / 64), 256, 0, stream>>>(
      oat, Wproj, bproj, (float*)d_out, CC, CC, 1);
}